// Round 2
// baseline (460.143 us; speedup 1.0000x reference)
//
#include <hip/hip_runtime.h>
#include <hip/hip_bf16.h>
#include <float.h>

// Problem constants (PQHotShared): U[16384,64], B[64,4096], codebook[2048,16]
static constexpr int KCB    = 2048;   // codebook entries
static constexpr int DSUB   = 16;    // subvector length
static constexpr int NSUB_U = 65536; // 16384*64/16
static constexpr int NSUB_B = 16384; // 64*4096/16
static constexpr int NSUB   = NSUB_U + NSUB_B; // 81920
static constexpr int NQ     = 4;     // codebook split for load balance
static constexpr int CPQ    = KCB / NQ; // 512
static constexpr int QMAX   = 320;   // per-wave refine queue capacity

typedef __attribute__((ext_vector_type(8))) short s16x8;   // 8 x bf16 (4 VGPRs)
typedef __attribute__((ext_vector_type(4))) float f32x4;

// ---------------- ws layout (bytes) ----------------
// BPACK overlays the UQH region: bpack is dead before pq_combine writes Uqh.
static constexpr size_t OFF_PBEST = 0;
static constexpr size_t OFF_PIDX  = 1310720;
static constexpr size_t OFF_C2    = 2621440;   // 8 KB
static constexpr size_t OFF_BPACK = 2629632;   // 128 KB (overlaps UQH)
static constexpr size_t OFF_UQH   = 2629632;
static constexpr size_t OFF_BQTH  = 4726784;

static __device__ __forceinline__ short bf16bits(float x) {
    __hip_bfloat16 h = __float2bfloat16(x);
    return *reinterpret_cast<short*>(&h);
}

// Prepack: (a) codebook -> bf16 MFMA B-fragments, zero-padded to K=32.
// Fragment mapping (same as verified mm_mfma): lane L supplies
// B[k=(L>>4)*8+j][n=L&15]; quads 2,3 (k>=16) are zero.
// Layout: bpack[((q*32+t)*64+L)] = 16 B frag, cw = q*512 + t*16 + (L&15).
// (b) ||c||^2 with the EXACT pairwise order of the original cb2_kernel.
__global__ __launch_bounds__(256) void pq_prepack(const float* __restrict__ cb,
                                                  short* __restrict__ bpack,
                                                  float* __restrict__ c2ws) {
    int idx = blockIdx.x * 256 + threadIdx.x;   // 0..8191
    int qq = idx >> 11;
    int t  = (idx >> 6) & 31;
    int L  = idx & 63;
    int qd = L >> 4, n = L & 15;
    int cw = qq * 512 + t * 16 + n;

    union { short s[8]; uint4 u; } w;
    if (qd < 2) {
        const float* p = cb + (size_t)cw * DSUB + qd * 8;
#pragma unroll
        for (int j = 0; j < 8; j++) w.s[j] = bf16bits(p[j]);
    } else {
        w.u = make_uint4(0u, 0u, 0u, 0u);
    }
    ((uint4*)bpack)[idx] = w.u;

    if (qd == 0) {
        const float* p = cb + (size_t)cw * DSUB;
        float a[16];
#pragma unroll
        for (int j = 0; j < 16; j++) { float v = p[j]; a[j] = fmaf(v, v, 0.0f); }
        float r[8];
#pragma unroll
        for (int j = 0; j < 8; j++) r[j] = a[j] + a[j + 8];
        c2ws[cw] = ((r[0] + r[1]) + (r[2] + r[3])) + ((r[4] + r[5]) + (r[6] + r[7]));
    }
}

// MFMA-prefiltered PQ argmin. One wave per (64-subvector group, codebook
// quarter). Pass 1: bf16 MFMA approx distances -> per-sub approx min m_a.
// Pass 2: flag ALL codewords with e_approx < m_a + eps_th (complete candidate
// set: |e_approx - e_exact| <= 2^-8*||g||*||c|| + accum << eps_th = 4e-3*||g||).
// Refine: exact reference chain (IEEE div f32 g, ascending fmaf, same c2),
// lex (e, idx) merge == first-index-wins. Bit-identical selection vs the
// previous passing kernel; overflow (never: E[q]~68 of 320) -> exact fallback.
__global__ __launch_bounds__(256) void pq_partial(
    const float* __restrict__ U, const float* __restrict__ B,
    const float* __restrict__ rsU, const float* __restrict__ rsB,
    const float* __restrict__ cb, const short* __restrict__ bpack,
    const float* __restrict__ c2ws,
    float* __restrict__ pbest, int* __restrict__ pidx)
{
    __shared__ short bpackS[32 * 64 * 8];      // 32 KB: quarter's B-frags
    __shared__ float c2S[CPQ];                 // 2 KB
    __shared__ float gS[4][64][20];            // 20.5 KB exact g rows (pad 20)
    __shared__ float mS[4][64];                // approx min per sub
    __shared__ float thrS[4][64];              // refine threshold per sub
    __shared__ int   qcntS[4];
    __shared__ unsigned qbufS[4][QMAX];
    __shared__ float qresS[4][QMAX];

    const int q     = blockIdx.x & 3;
    const int chunk = blockIdx.x >> 2;         // 0..319
    const int wave  = __builtin_amdgcn_readfirstlane(threadIdx.x >> 6);
    const int lane  = threadIdx.x & 63;
    const int qd    = lane >> 4;
    const int n15   = lane & 15;

    // ---- stage B-frags + c2 for this quarter ----
    {
        const uint4* src = ((const uint4*)bpack) + (size_t)q * 2048;
        uint4* dst = (uint4*)bpackS;
#pragma unroll
        for (int i = 0; i < 8; i++)
            dst[i * 256 + threadIdx.x] = src[i * 256 + threadIdx.x];
        const float* c2src = c2ws + q * CPQ;
#pragma unroll
        for (int i = 0; i < 2; i++)
            c2S[i * 256 + threadIdx.x] = c2src[i * 256 + threadIdx.x];
    }

    // ---- exact g for this wave's 64 subs (lane owns sub==lane) ----
    const int sub_g = chunk * 256 + wave * 64 + lane;
    float gn = 0.0f;
    {
        const float* wp; float rs_;
        if (sub_g < NSUB_U) { wp = U + (size_t)sub_g * DSUB; rs_ = rsU[sub_g >> 2]; }
        else { int s2 = sub_g - NSUB_U; wp = B + (size_t)s2 * DSUB; rs_ = rsB[s2 >> 8]; }
        float g[16];
#pragma unroll
        for (int k = 0; k < 16; k++) { g[k] = wp[k] / rs_; gn = fmaf(g[k], g[k], gn); }
#pragma unroll
        for (int k4 = 0; k4 < 4; k4++)
            *(f32x4*)&gS[wave][lane][k4 * 4] = *(f32x4*)&g[k4 * 4];
    }
    if (lane == 0) qcntS[wave] = 0;
    __syncthreads();

    // ---- A-fragments (bf16 of g), zero-padded upper K ----
    s16x8 Ah[4];
#pragma unroll
    for (int T = 0; T < 4; T++) {
        s16x8 a;
        if (qd < 2) {
            const float* gp = &gS[wave][T * 16 + n15][qd * 8];
#pragma unroll
            for (int j = 0; j < 8; j++) a[j] = bf16bits(gp[j]);
        } else {
#pragma unroll
            for (int j = 0; j < 8; j++) a[j] = 0;
        }
        Ah[T] = a;
    }

    const s16x8* bS = (const s16x8*)bpackS;

    // ---- pass 1: approx distances, per-slot running min ----
    float bestv[4][4];
#pragma unroll
    for (int T = 0; T < 4; T++)
#pragma unroll
        for (int r = 0; r < 4; r++) bestv[T][r] = FLT_MAX;

#pragma unroll 4
    for (int t = 0; t < 32; t++) {
        s16x8 bh = bS[t * 64 + lane];
        float c2v = c2S[t * 16 + n15];
#pragma unroll
        for (int T = 0; T < 4; T++) {
            f32x4 acc = {0.f, 0.f, 0.f, 0.f};
            acc = __builtin_amdgcn_mfma_f32_16x16x32_bf16(Ah[T], bh, acc, 0, 0, 0);
#pragma unroll
            for (int r = 0; r < 4; r++)
                bestv[T][r] = fminf(bestv[T][r], fmaf(-2.0f, acc[r], c2v));
        }
    }

    // ---- reduce across the 16 n-lanes -> m_a per sub ----
#pragma unroll
    for (int T = 0; T < 4; T++)
#pragma unroll
        for (int r = 0; r < 4; r++) {
#pragma unroll
            for (int m = 1; m < 16; m <<= 1)
                bestv[T][r] = fminf(bestv[T][r], __shfl_xor(bestv[T][r], m, 64));
        }
    if (n15 == 0) {
#pragma unroll
        for (int T = 0; T < 4; T++)
#pragma unroll
            for (int r = 0; r < 4; r++)
                mS[wave][T * 16 + qd * 4 + r] = bestv[T][r];
    }
    __syncthreads();
    // threshold: eps_th = 4e-3*||g|| (>=3x the rigorous bf16 error bound)
    thrS[wave][lane] = mS[wave][lane] + fmaf(4e-3f, sqrtf(gn), 1e-10f);
    __syncthreads();

    float thr[4][4];
#pragma unroll
    for (int T = 0; T < 4; T++)
#pragma unroll
        for (int r = 0; r < 4; r++)
            thr[T][r] = thrS[wave][T * 16 + qd * 4 + r];

    // ---- pass 2: recompute, queue every candidate below threshold ----
#pragma unroll 4
    for (int t = 0; t < 32; t++) {
        s16x8 bh = bS[t * 64 + lane];
        float c2v = c2S[t * 16 + n15];
#pragma unroll
        for (int T = 0; T < 4; T++) {
            f32x4 acc = {0.f, 0.f, 0.f, 0.f};
            acc = __builtin_amdgcn_mfma_f32_16x16x32_bf16(Ah[T], bh, acc, 0, 0, 0);
#pragma unroll
            for (int r = 0; r < 4; r++) {
                float e = fmaf(-2.0f, acc[r], c2v);
                bool h = e < thr[T][r];
                if (__ballot(h)) {
                    if (h) {
                        int pos = atomicAdd(&qcntS[wave], 1);
                        if (pos < QMAX)
                            qbufS[wave][pos] =
                                ((unsigned)(T * 16 + qd * 4 + r) << 16) |
                                (unsigned)(t * 16 + n15);
                    }
                }
            }
        }
    }
    __syncthreads();

    int qc = qcntS[wave];
    if (qc <= QMAX) {
        // ---- exact refine of all candidates (reference op order) ----
        for (int i = lane; i < qc; i += 64) {
            unsigned ent = qbufS[wave][i];
            int sl = (int)(ent >> 16);
            int cwl = (int)(ent & 0xffffu);
            const float* gp = &gS[wave][sl][0];
            const float* cp = cb + (size_t)(q * CPQ + cwl) * DSUB;
            float d = 0.0f;
#pragma unroll
            for (int k = 0; k < 16; k++) d = fmaf(gp[k], cp[k], d);
            qresS[wave][i] = fmaf(-2.0f, d, c2S[cwl]);
        }
        __threadfence_block();
        // ---- lex merge (strict <, tie -> lower idx) == first-index-wins ----
        float bst = FLT_MAX; int bci = 0x7fffffff;
        for (int i = 0; i < qc; i++) {
            unsigned ent = qbufS[wave][i];
            if ((int)(ent >> 16) == lane) {
                float e = qresS[wave][i];
                int cwl = (int)(ent & 0xffffu);
                if (e < bst || (e == bst && cwl < bci)) { bst = e; bci = cwl; }
            }
        }
        pbest[(size_t)sub_g * 4 + q] = bst;
        pidx[(size_t)sub_g * 4 + q]  = q * CPQ + bci;
    } else {
        // ---- overflow fallback: full exact scan (never expected) ----
        float g2[16];
#pragma unroll
        for (int k = 0; k < 16; k++) g2[k] = gS[wave][lane][k];
        float bst = FLT_MAX; int bci = 0;
#pragma unroll 1
        for (int c = 0; c < CPQ; c++) {
            const float* cp = cb + (size_t)(q * CPQ + c) * DSUB;
            float d = 0.0f;
#pragma unroll
            for (int k = 0; k < 16; k++) d = fmaf(g2[k], cp[k], d);
            float e = fmaf(-2.0f, d, c2S[c]);
            if (e < bst) { bst = e; bci = c; }
        }
        pbest[(size_t)sub_g * 4 + q] = bst;
        pidx[(size_t)sub_g * 4 + q]  = q * CPQ + bci;
    }
}

// Merge the 4 quarter-results (in order -> first-index tie semantics),
// dequantize, cast to bf16. Uq stored [16384][64] row-major; Bq stored
// transposed as BqT [4096 cols][64 k] for MFMA B-fragment loads.
__global__ __launch_bounds__(256) void pq_combine(
    const float* __restrict__ cb,
    const float* __restrict__ rsU, const float* __restrict__ rsB,
    const float* __restrict__ pbest, const int* __restrict__ pidx,
    __hip_bfloat16* __restrict__ Uqh, __hip_bfloat16* __restrict__ BqTh)
{
    int sub = blockIdx.x * 256 + threadIdx.x;   // < 81920 exactly
    float4 b4 = ((const float4*)pbest)[sub];
    int4   i4 = ((const int4*)pidx)[sub];
    float best = b4.x; int bi = i4.x;
    if (b4.y < best) { best = b4.y; bi = i4.y; }
    if (b4.z < best) { best = b4.z; bi = i4.z; }
    if (b4.w < best) { best = b4.w; bi = i4.w; }

    const float* cp = cb + (size_t)bi * DSUB;
    if (sub < NSUB_U) {
        float rs = rsU[sub >> 2];
        union { __hip_bfloat16 h[16]; uint4 u4[2]; } u;
#pragma unroll
        for (int j = 0; j < 16; j++) u.h[j] = __float2bfloat16(cp[j] * rs);
        uint4* dst = (uint4*)(Uqh + (size_t)sub * DSUB);
        dst[0] = u.u4[0];
        dst[1] = u.u4[1];
    } else {
        int s = sub - NSUB_U;
        int kk = s >> 8;                 // B row (k index), 0..63
        int dbase = (s & 255) * DSUB;    // output column base
        float rs = rsB[kk];
#pragma unroll
        for (int j = 0; j < 16; j++)
            BqTh[(size_t)(dbase + j) * 64 + kk] = __float2bfloat16(cp[j] * rs);
    }
}

// C[16384,4096] = Uq @ Bq via mfma_f32_16x16x32_bf16, K=64 (2 mfma per tile).
// One wave computes a 16-row x 64-col strip (4 n-tiles). HBM-write-bound;
// nontemporal stores keep C from churning L2.
__global__ __launch_bounds__(256) void mm_mfma(
    const __hip_bfloat16* __restrict__ A,   // [16384][64]
    const __hip_bfloat16* __restrict__ BT,  // [4096][64]
    float* __restrict__ C)
{
    int wave = threadIdx.x >> 6;
    int lane = threadIdx.x & 63;
    int rb  = ((blockIdx.y << 2) | wave) << 4;   // row base, 16 rows
    int cb0 = blockIdx.x << 6;                   // col base, 64 cols
    int mrow = lane & 15;
    int quad = lane >> 4;
    int kidx = quad * 8;

    const s16x8* ap = (const s16x8*)(A + (size_t)(rb + mrow) * 64 + kidx);
    s16x8 a0 = ap[0];     // k in [kidx, kidx+8)
    s16x8 a1 = ap[4];     // k in [32+kidx, 32+kidx+8)

    f32x4 acc[4] = {};
#pragma unroll
    for (int nt = 0; nt < 4; nt++) {
        const s16x8* bp =
            (const s16x8*)(BT + (size_t)(cb0 + nt * 16 + mrow) * 64 + kidx);
        s16x8 b0 = bp[0];
        s16x8 b1 = bp[4];
        acc[nt] = __builtin_amdgcn_mfma_f32_16x16x32_bf16(a0, b0, acc[nt], 0, 0, 0);
        acc[nt] = __builtin_amdgcn_mfma_f32_16x16x32_bf16(a1, b1, acc[nt], 0, 0, 0);
    }

#pragma unroll
    for (int nt = 0; nt < 4; nt++) {
#pragma unroll
        for (int i = 0; i < 4; i++) {
            __builtin_nontemporal_store(
                acc[nt][i],
                &C[(size_t)(rb + quad * 4 + i) * 4096 + (cb0 + nt * 16 + mrow)]);
        }
    }
}

extern "C" void kernel_launch(void* const* d_in, const int* in_sizes, int n_in,
                              void* d_out, int out_size, void* d_ws, size_t ws_size,
                              hipStream_t stream) {
    const float* U    = (const float*)d_in[0];   // [16384,64]
    const float* B    = (const float*)d_in[1];   // [64,4096]
    const float* rsU  = (const float*)d_in[2];   // [16384,1]
    const float* rsB  = (const float*)d_in[3];   // [64,1]
    const float* cb   = (const float*)d_in[4];   // [2048,16]
    float* C = (float*)d_out;                    // [16384,4096]

    char* w = (char*)d_ws;                       // needs ~5.25 MB
    float* pbest = (float*)(w + OFF_PBEST);
    int*   pidx  = (int*)(w + OFF_PIDX);
    float* c2ws  = (float*)(w + OFF_C2);
    short* bpack = (short*)(w + OFF_BPACK);
    __hip_bfloat16* Uqh  = (__hip_bfloat16*)(w + OFF_UQH);
    __hip_bfloat16* BqTh = (__hip_bfloat16*)(w + OFF_BQTH);

    pq_prepack<<<32, 256, 0, stream>>>(cb, bpack, c2ws);
    pq_partial<<<(NSUB / 256) * NQ, 256, 0, stream>>>(U, B, rsU, rsB, cb, bpack,
                                                      c2ws, pbest, pidx);
    pq_combine<<<NSUB / 256, 256, 0, stream>>>(cb, rsU, rsB, pbest, pidx,
                                               Uqh, BqTh);
    mm_mfma<<<dim3(64, 256), 256, 0, stream>>>(Uqh, BqTh, C);
}